// Round 6
// baseline (813.345 us; speedup 1.0000x reference)
//
#include <hip/hip_runtime.h>
#include <math.h>

typedef unsigned short u16;
typedef unsigned int u32;
typedef short short8 __attribute__((ext_vector_type(8)));
typedef float f32x4 __attribute__((ext_vector_type(4)));

#define B_ 8
#define S_ 2048
#define D_ 512
#define N_ (B_ * S_)
#define ND_ ((size_t)N_ * D_)
#define CC_ 32              // chunk length
#define NC_ (S_ / CC_)      // 64 chunks
#define SV_ 8               // v-rows per scan block

__device__ __forceinline__ u16 f2bf(float f) {
  union { float f; u32 i; } v; v.f = f;
  u32 i = v.i;
  i += 0x7FFFu + ((i >> 16) & 1u);   // round-to-nearest-even
  return (u16)(i >> 16);
}
__device__ __forceinline__ float sigm(float x) { return 1.0f / (1.0f + expf(-x)); }

// ---------------------------------------------------------------------------
// f32 -> bf16 conversion
// ---------------------------------------------------------------------------
__global__ __launch_bounds__(256) void cvt_bf16(const float* __restrict__ s,
                                                u16* __restrict__ d, int n)
{
  const int i = (blockIdx.x * 256 + threadIdx.x) * 4;
  if (i < n) {
    const float4 v = *(const float4*)(s + i);
    ushort4 o;
    o.x = f2bf(v.x); o.y = f2bf(v.y); o.z = f2bf(v.z); o.w = f2bf(v.w);
    *(ushort4*)(d + i) = o;
  }
}

// ---------------------------------------------------------------------------
// GEMM: out[m,n] = sum_k A[m,k]*W[n,k] + bias[n]; bf16 in, f32 out.
// ---------------------------------------------------------------------------
__global__ __launch_bounds__(256) void gemm_bt(
    const u16* __restrict__ A, const u16* __restrict__ W,
    const float* __restrict__ bias, float* __restrict__ out)
{
  __shared__ u16 As[128 * 40];
  __shared__ u16 Bs[128 * 40];
  const int tid = threadIdx.x;
  const int lane = tid & 63, wave = tid >> 6;
  const int wm = (wave >> 1) * 64, wn = (wave & 1) * 64;
  const int l15 = lane & 15, quad = lane >> 4;
  const int m0 = blockIdx.x * 128, n0 = blockIdx.y * 128;
  const int r0 = tid >> 2;
  const int kc0 = (tid & 3) * 8;

  f32x4 acc[4][4];
#pragma unroll
  for (int i = 0; i < 4; i++)
#pragma unroll
    for (int j = 0; j < 4; j++) acc[i][j] = (f32x4){0.f, 0.f, 0.f, 0.f};

  for (int k0 = 0; k0 < 512; k0 += 32) {
    uint4 a0 = *(const uint4*)(A + (size_t)(m0 + r0) * 512 + k0 + kc0);
    uint4 a1 = *(const uint4*)(A + (size_t)(m0 + r0 + 64) * 512 + k0 + kc0);
    uint4 b0 = *(const uint4*)(W + (size_t)(n0 + r0) * 512 + k0 + kc0);
    uint4 b1 = *(const uint4*)(W + (size_t)(n0 + r0 + 64) * 512 + k0 + kc0);
    __syncthreads();
    *(uint4*)(As + r0 * 40 + kc0) = a0;
    *(uint4*)(As + (r0 + 64) * 40 + kc0) = a1;
    *(uint4*)(Bs + r0 * 40 + kc0) = b0;
    *(uint4*)(Bs + (r0 + 64) * 40 + kc0) = b1;
    __syncthreads();
    short8 af[4], bf[4];
#pragma unroll
    for (int mt = 0; mt < 4; mt++) af[mt] = *(const short8*)(As + (wm + mt * 16 + l15) * 40 + quad * 8);
#pragma unroll
    for (int nt = 0; nt < 4; nt++) bf[nt] = *(const short8*)(Bs + (wn + nt * 16 + l15) * 40 + quad * 8);
#pragma unroll
    for (int mt = 0; mt < 4; mt++)
#pragma unroll
      for (int nt = 0; nt < 4; nt++)
        acc[mt][nt] = __builtin_amdgcn_mfma_f32_16x16x32_bf16(af[mt], bf[nt], acc[mt][nt], 0, 0, 0);
  }
#pragma unroll
  for (int mt = 0; mt < 4; mt++) {
#pragma unroll
    for (int nt = 0; nt < 4; nt++) {
      const int col = n0 + wn + nt * 16 + l15;
      const float bcol = bias[col];
#pragma unroll
      for (int r = 0; r < 4; r++) {
        const int row = m0 + wm + mt * 16 + quad * 4 + r;
        out[(size_t)row * 512 + col] = acc[mt][nt][r] + bcol;
      }
    }
  }
}

// ---------------------------------------------------------------------------
// alpha/beta
// ---------------------------------------------------------------------------
__global__ __launch_bounds__(256) void ab_kernel(
    const float* __restrict__ x, const float* __restrict__ Wa, const float* __restrict__ ba,
    const float* __restrict__ Wb, const float* __restrict__ bb,
    float* __restrict__ alpha, float* __restrict__ beta)
{
  const int lane = threadIdx.x & 63, wave = threadIdx.x >> 6;
  const int row = blockIdx.x * 4 + wave;
  const float4 x0 = *(const float4*)(x + (size_t)row * 512 + lane * 8);
  const float4 x1 = *(const float4*)(x + (size_t)row * 512 + lane * 8 + 4);
  const float4 a0 = *(const float4*)(Wa + lane * 8);
  const float4 a1 = *(const float4*)(Wa + lane * 8 + 4);
  const float4 b0 = *(const float4*)(Wb + lane * 8);
  const float4 b1 = *(const float4*)(Wb + lane * 8 + 4);
  float da = x0.x*a0.x + x0.y*a0.y + x0.z*a0.z + x0.w*a0.w
           + x1.x*a1.x + x1.y*a1.y + x1.z*a1.z + x1.w*a1.w;
  float db = x0.x*b0.x + x0.y*b0.y + x0.z*b0.z + x0.w*b0.w
           + x1.x*b1.x + x1.y*b1.y + x1.z*b1.z + x1.w*b1.w;
#pragma unroll
  for (int m = 32; m >= 1; m >>= 1) { da += __shfl_xor(da, m, 64); db += __shfl_xor(db, m, 64); }
  if (lane == 0) {
    alpha[row] = sigm(da + ba[0]);
    beta[row]  = sigm(db + bb[0]);
  }
}

// ---------------------------------------------------------------------------
// causal depthwise conv (k=4) + SiLU (+ L2 norm for q,k -> bf16; v -> f32)
// ---------------------------------------------------------------------------
__global__ __launch_bounds__(256) void conv_act(
    const float* __restrict__ lq, const float* __restrict__ lk, const float* __restrict__ lv,
    const float* __restrict__ cwq, const float* __restrict__ cbq,
    const float* __restrict__ cwk, const float* __restrict__ cbk,
    const float* __restrict__ cwv, const float* __restrict__ cbv,
    u16* __restrict__ oq, u16* __restrict__ ok, float* __restrict__ ov)
{
  __shared__ float red[4];
  const int row = blockIdx.x;
  const int z = blockIdx.y;
  const int b = row / S_, t = row - b * S_;
  const float* lin = (z == 0) ? lq : (z == 1) ? lk : lv;
  const float* cw = (z == 0) ? cwq : (z == 1) ? cwk : cwv;
  const float* cb = (z == 0) ? cbq : (z == 1) ? cbk : cbv;
  const int tid = threadIdx.x;
  float s[2]; float ssq = 0.f;
#pragma unroll
  for (int e = 0; e < 2; e++) {
    const int ch = tid + e * 256;
    float acc = cb[ch];
#pragma unroll
    for (int tau = 0; tau < 4; tau++) {
      const int tt = t - 3 + tau;
      if (tt >= 0) acc = fmaf(lin[(size_t)(b * S_ + tt) * D_ + ch], cw[ch * 4 + tau], acc);
    }
    const float sv = acc * sigm(acc);
    s[e] = sv; ssq = fmaf(sv, sv, ssq);
  }
  if (z < 2) {
    float v = ssq;
#pragma unroll
    for (int m = 32; m >= 1; m >>= 1) v += __shfl_xor(v, m, 64);
    if ((tid & 63) == 0) red[tid >> 6] = v;
    __syncthreads();
    const float tot = red[0] + red[1] + red[2] + red[3];
    const float scale = 1.0f / fmaxf(sqrtf(tot), 1e-12f);
    u16* outp = (z == 0) ? oq : ok;
    outp[(size_t)row * D_ + tid] = f2bf(s[0] * scale);
    outp[(size_t)row * D_ + tid + 256] = f2bf(s[1] * scale);
  } else {
    ov[(size_t)row * D_ + tid] = s[0];
    ov[(size_t)row * D_ + tid + 256] = s[1];
  }
}

// ---------------------------------------------------------------------------
// transpose kh [b,t,ch] -> khT [b,ch,t]  (bf16), 64x64 tiles
// ---------------------------------------------------------------------------
__global__ __launch_bounds__(256) void transpose_k(
    const u16* __restrict__ kh, u16* __restrict__ khT)
{
  __shared__ u16 T[64][68];
  const int b = blockIdx.z;
  const int t0 = blockIdx.x * 64;
  const int c0 = blockIdx.y * 64;
  const int tid = threadIdx.x;
  const int tr = tid >> 4;
  const int c4 = (tid & 15) * 4;
#pragma unroll
  for (int i = 0; i < 4; i++) {
    const int t = tr + i * 16;
    ushort4 v = *(const ushort4*)(kh + ((size_t)(b * S_ + t0 + t)) * 512 + c0 + c4);
    T[c4 + 0][t] = v.x; T[c4 + 1][t] = v.y; T[c4 + 2][t] = v.z; T[c4 + 3][t] = v.w;
  }
  __syncthreads();
#pragma unroll
  for (int i = 0; i < 4; i++) {
    const int ch = tr + i * 16;
    ushort4 v = *(const ushort4*)&T[ch][c4];
    *(ushort4*)(khT + ((size_t)(b * 512 + c0 + ch)) * S_ + t0 + c4) = v;
  }
}

// ---------------------------------------------------------------------------
// prepass: per (b,chunk) build X=(I+M)^-1 (bf16), A matrix (bf16), gamma tables
// ---------------------------------------------------------------------------
__global__ __launch_bounds__(256) void prepass(
    const u16* __restrict__ kh, const u16* __restrict__ qh,
    const float* __restrict__ alpha, const float* __restrict__ beta,
    u16* __restrict__ Xg, u16* __restrict__ Ag, float* __restrict__ gg)
{
  __shared__ float KK[32][33];
  __shared__ float QK[32][33];
  __shared__ float Ml[32][33];
  __shared__ float Xs[32][33];
  __shared__ float lg[32], cum[32], bet[32];
  const int bc = blockIdx.x;
  const int b = bc >> 6, c = bc & 63;
  const int t0 = c * CC_;
  const int tid = threadIdx.x, lane = tid & 63, w = tid >> 6;
  const int l15 = lane & 15, quad = lane >> 4;
  const size_t rb = (size_t)b * S_ + t0;

  if (tid < 32) { lg[tid] = logf(alpha[b * S_ + t0 + tid]); bet[tid] = beta[b * S_ + t0 + tid]; }
  __syncthreads();
  if (tid < 32) {
    float s = 0.f;
    for (int u = 0; u <= tid; u++) s += lg[u];
    cum[tid] = s;
  }
  const int mi = w >> 1, ni = w & 1;
  f32x4 ck = (f32x4){0.f,0.f,0.f,0.f}, cq = ck;
#pragma unroll
  for (int kt = 0; kt < 16; kt++) {
    const int kc = kt * 32 + quad * 8;
    short8 afk = *(const short8*)(kh + (rb + mi * 16 + l15) * 512 + kc);
    short8 afq = *(const short8*)(qh + (rb + mi * 16 + l15) * 512 + kc);
    short8 bk  = *(const short8*)(kh + (rb + ni * 16 + l15) * 512 + kc);
    ck = __builtin_amdgcn_mfma_f32_16x16x32_bf16(afk, bk, ck, 0, 0, 0);
    cq = __builtin_amdgcn_mfma_f32_16x16x32_bf16(afq, bk, cq, 0, 0, 0);
  }
#pragma unroll
  for (int r = 0; r < 4; r++) {
    KK[mi * 16 + quad * 4 + r][ni * 16 + l15] = ck[r];
    QK[mi * 16 + quad * 4 + r][ni * 16 + l15] = cq[r];
  }
  __syncthreads();
  if (tid < 32) {
    gg[(size_t)bc * 64 + tid] = expf(cum[tid]);
    gg[(size_t)bc * 64 + 32 + tid] = expf(cum[31] - cum[tid]);
  }
#pragma unroll
  for (int rep = 0; rep < 4; rep++) {
    const int e = tid + rep * 256;
    const int t = e >> 5, s = e & 31;
    const float er = expf(cum[t] - cum[s]);
    Ml[t][s] = (s < t) ? bet[t] * er * KK[t][s] : 0.f;
    Ag[(size_t)bc * 1024 + t * 32 + s] = (s <= t) ? f2bf(QK[t][s] * er) : (u16)0;
  }
  __syncthreads();
  if (w == 0 && lane < 32) {
    const int j = lane;
    Xs[0][j] = (j == 0) ? 1.f : 0.f;
    for (int t = 1; t < 32; t++) {
      float a = (t == j) ? 1.f : 0.f;
      for (int u = 0; u < t; u++) a = fmaf(-Ml[t][u], Xs[u][j], a);
      Xs[t][j] = a;
    }
  }
  __syncthreads();
#pragma unroll
  for (int rep = 0; rep < 4; rep++) {
    const int e = tid + rep * 256;
    const int t = e >> 5, s = e & 31;
    Xg[(size_t)bc * 1024 + t * 32 + s] = f2bf(Xs[t][s]);
  }
}

// ---------------------------------------------------------------------------
// chunked gated-delta scan, v2: 512 thr (8 waves), SV_=8 v-rows/block,
// grid (64 slices, 8 batches) = 512 blocks -> 2 blocks/CU, 16 waves/CU.
// Wave w owns k-rows [w*64, w*64+64) (4 m-tiles). All global loads for a
// chunk are issued before the first barrier of the iteration.
// ---------------------------------------------------------------------------
__global__ __launch_bounds__(512, 4) void scan_chunk(
    const u16* __restrict__ kh, const u16* __restrict__ qh,
    const u16* __restrict__ khT, const float* __restrict__ vb,
    const float* __restrict__ beta, const u16* __restrict__ Xg,
    const u16* __restrict__ Ag, const float* __restrict__ gg,
    float* __restrict__ gdn)
{
  __shared__ u16 S_A[16 * 520];       // S[v][k] bf16 (16 v rows, 8 valid)
  __shared__ float PA[8][32][16];     // G_A^T partials [wave][s][v]
  __shared__ float PB[8][32][16];
  __shared__ u16 R_T[16 * 40];        // Btilde*R^T [v][s]
  __shared__ u16 Ct_T[16 * 40];       // C~^T [v][s]
  __shared__ u16 Cr_T[16 * 40];       // C~^T * (gC/gs)
  __shared__ float OB[32][16];        // gamma_t * G_B^T reduced [t][v]
  __shared__ float O_s[32][20];       // staged output [t][v]
  __shared__ float gam[32], grc[32];
  const int b = blockIdx.y;
  const int iv0 = blockIdx.x * SV_;
  const int tid = threadIdx.x, lane = tid & 63, w = tid >> 6;   // w 0..7
  const int l15 = lane & 15, quad = lane >> 4;
  const size_t bS = (size_t)b * S_;
  const int cs = (tid & 255) >> 3, cv = tid & 7;   // phase-C elem (tid<256)

  // zero-init LDS that is read before first full write (v>=8 rows + OB)
  if (tid < 320) { R_T[tid] = 0; R_T[tid + 320] = 0;
                   Ct_T[tid] = 0; Ct_T[tid + 320] = 0;
                   Cr_T[tid] = 0; Cr_T[tid + 320] = 0; }
  else if (tid < 512) { const int e = tid - 320;   // 192 threads
    ((float*)OB)[e] = 0.f; ((float*)OB)[e + 192] = 0.f;
    if (e < 128) ((float*)OB)[e + 384] = 0.f; }

  f32x4 acc[4];
#pragma unroll
  for (int mt = 0; mt < 4; mt++) acc[mt] = (f32x4){0.f, 0.f, 0.f, 0.f};

#pragma unroll 1
  for (int c = 0; c < NC_; c++) {
    const int t0 = c * CC_;
    const int bc = b * 64 + c;
    // ---- phase A: issue ALL global loads for this chunk first ----
    short8 pk[2][2], pq[2][2], tk[4];
#pragma unroll
    for (int kt = 0; kt < 2; kt++)
#pragma unroll
      for (int nt = 0; nt < 2; nt++) {
        const size_t rowk = (bS + t0 + nt * 16 + l15) * 512 + w * 64 + kt * 32 + quad * 8;
        pk[kt][nt] = *(const short8*)(kh + rowk);
        pq[kt][nt] = *(const short8*)(qh + rowk);
      }
#pragma unroll
    for (int mt = 0; mt < 4; mt++)
      tk[mt] = *(const short8*)(khT + ((size_t)(b * 512 + w * 64 + mt * 16 + l15)) * S_ + t0 + quad * 8);
    float vv = 0.f, bt = 0.f;
    if (tid < 256) {
      vv = vb[(bS + t0 + cs) * 512 + iv0 + cv];
      bt = beta[bS + t0 + cs];
    }
    if (tid < 32) { gam[tid] = gg[(size_t)bc * 64 + tid]; grc[tid] = gg[(size_t)bc * 64 + 32 + tid]; }
    // dump state (bf16) to LDS
#pragma unroll
    for (int mt = 0; mt < 4; mt++) {
      ushort4 p;
      p.x = f2bf(acc[mt][0]); p.y = f2bf(acc[mt][1]);
      p.z = f2bf(acc[mt][2]); p.w = f2bf(acc[mt][3]);
      *(ushort4*)&S_A[l15 * 520 + w * 64 + mt * 16 + quad * 4] = p;
    }
    __syncthreads();
    // ---- phase B: G_A^T, G_B^T partials over this wave's 64 k-cols ----
    f32x4 ga[2], gb[2];
    ga[0] = ga[1] = gb[0] = gb[1] = (f32x4){0.f, 0.f, 0.f, 0.f};
#pragma unroll
    for (int kt = 0; kt < 2; kt++) {
      short8 af = *(const short8*)&S_A[l15 * 520 + w * 64 + kt * 32 + quad * 8];
#pragma unroll
      for (int nt = 0; nt < 2; nt++) {
        ga[nt] = __builtin_amdgcn_mfma_f32_16x16x32_bf16(af, pk[kt][nt], ga[nt], 0, 0, 0);
        gb[nt] = __builtin_amdgcn_mfma_f32_16x16x32_bf16(af, pq[kt][nt], gb[nt], 0, 0, 0);
      }
    }
#pragma unroll
    for (int nt = 0; nt < 2; nt++) {
      const int s = nt * 16 + l15;
      *(f32x4*)&PA[w][s][quad * 4] = ga[nt];
      *(f32x4*)&PB[w][s][quad * 4] = gb[nt];
    }
    __syncthreads();
    // ---- phase C: reduce partials, build R~^T and OB; flush prev O ----
    const float gCs = gam[31];          // snapshot (race-safe window)
    if (tid < 256) {
      float sa = PA[0][cs][cv] + PA[1][cs][cv] + PA[2][cs][cv] + PA[3][cs][cv]
               + PA[4][cs][cv] + PA[5][cs][cv] + PA[6][cs][cv] + PA[7][cs][cv];
      float sb = PB[0][cs][cv] + PB[1][cs][cv] + PB[2][cs][cv] + PB[3][cs][cv]
               + PB[4][cs][cv] + PB[5][cs][cv] + PB[6][cs][cv] + PB[7][cs][cv];
      const float g = gam[cs];
      R_T[cv * 40 + cs] = f2bf(bt * (vv - g * sa));
      OB[cs][cv] = g * sb;
      if (c > 0) gdn[(bS + t0 - CC_ + cs) * 512 + iv0 + cv] = O_s[cs][cv];
    }
    __syncthreads();
    // ---- phase D: wave0 solves C~^T = R~^T X^T ----
    if (w == 0) {
      short8 af = *(const short8*)&R_T[l15 * 40 + quad * 8];
      f32x4 cc[2];
      cc[0] = cc[1] = (f32x4){0.f, 0.f, 0.f, 0.f};
#pragma unroll
      for (int nt = 0; nt < 2; nt++) {
        short8 bx = *(const short8*)(Xg + (size_t)bc * 1024 + (nt * 16 + l15) * 32 + quad * 8);
        cc[nt] = __builtin_amdgcn_mfma_f32_16x16x32_bf16(af, bx, cc[nt], 0, 0, 0);
      }
#pragma unroll
      for (int nt = 0; nt < 2; nt++) {
        const int t = nt * 16 + l15;
        const float gr = grc[t];
#pragma unroll
        for (int r = 0; r < 4; r++) {
          Ct_T[(quad * 4 + r) * 40 + t] = f2bf(cc[nt][r]);
          Cr_T[(quad * 4 + r) * 40 + t] = f2bf(cc[nt][r] * gr);
        }
      }
    }
    __syncthreads();
    // ---- phase F: state update GEMM (all waves); wave0 also O GEMM ----
    short8 bcf = *(const short8*)&Cr_T[l15 * 40 + quad * 8];
#pragma unroll
    for (int mt = 0; mt < 4; mt++) {
      acc[mt] = acc[mt] * gCs;
      acc[mt] = __builtin_amdgcn_mfma_f32_16x16x32_bf16(tk[mt], bcf, acc[mt], 0, 0, 0);
    }
    if (w == 0) {
      short8 af = *(const short8*)&Ct_T[l15 * 40 + quad * 8];
#pragma unroll
      for (int nt = 0; nt < 2; nt++) {
        const int t = nt * 16 + l15;
        f32x4 oo = *(const f32x4*)&OB[t][quad * 4];
        short8 ba = *(const short8*)(Ag + (size_t)bc * 1024 + t * 32 + quad * 8);
        oo = __builtin_amdgcn_mfma_f32_16x16x32_bf16(af, ba, oo, 0, 0, 0);
        *(f32x4*)&O_s[t][quad * 4] = oo;
      }
    }
  }
  __syncthreads();
  // final O flush (chunk NC_-1)
  if (tid < 256)
    gdn[(bS + (NC_ - 1) * CC_ + cs) * 512 + iv0 + cv] = O_s[cs][cv];
}

// ---------------------------------------------------------------------------
// zero-centered rmsnorm * norm_w * silu(gate) -> bf16 h
// ---------------------------------------------------------------------------
__global__ __launch_bounds__(256) void norm_gate(
    const float* __restrict__ gdn, const float* __restrict__ lg,
    const float* __restrict__ nw, u16* __restrict__ h)
{
  __shared__ float red[8];
  const int row = blockIdx.x, tid = threadIdx.x;
  const size_t base = (size_t)row * D_;
  const float g0 = gdn[base + tid], g1 = gdn[base + tid + 256];
  float sm = g0 + g1;
#pragma unroll
  for (int m = 32; m >= 1; m >>= 1) sm += __shfl_xor(sm, m, 64);
  if ((tid & 63) == 0) red[tid >> 6] = sm;
  __syncthreads();
  const float mean = (red[0] + red[1] + red[2] + red[3]) * (1.0f / 512.0f);
  const float x0 = g0 - mean, x1 = g1 - mean;
  float sq = x0 * x0 + x1 * x1;
#pragma unroll
  for (int m = 32; m >= 1; m >>= 1) sq += __shfl_xor(sq, m, 64);
  if ((tid & 63) == 0) red[4 + (tid >> 6)] = sq;
  __syncthreads();
  const float var = (red[4] + red[5] + red[6] + red[7]) * (1.0f / 512.0f);
  const float rst = rsqrtf(var + 1e-5f);
  const float gl0 = lg[base + tid];
  h[base + tid] = f2bf(x0 * rst * nw[tid] * (gl0 * sigm(gl0)));
  const float gl1 = lg[base + tid + 256];
  h[base + tid + 256] = f2bf(x1 * rst * nw[tid + 256] * (gl1 * sigm(gl1)));
}

// ---------------------------------------------------------------------------
extern "C" void kernel_launch(void* const* d_in, const int* in_sizes, int n_in,
                              void* d_out, int out_size, void* d_ws, size_t ws_size,
                              hipStream_t stream)
{
  const float* x   = (const float*)d_in[0];
  const float* Wq  = (const float*)d_in[1];
  const float* bq  = (const float*)d_in[2];
  const float* Wk  = (const float*)d_in[3];
  const float* bk  = (const float*)d_in[4];
  const float* Wv  = (const float*)d_in[5];
  const float* bv  = (const float*)d_in[6];
  const float* Wa  = (const float*)d_in[7];
  const float* ba  = (const float*)d_in[8];
  const float* Wb  = (const float*)d_in[9];
  const float* bb  = (const float*)d_in[10];
  const float* cwq = (const float*)d_in[11];
  const float* cbq = (const float*)d_in[12];
  const float* cwk = (const float*)d_in[13];
  const float* cbk = (const float*)d_in[14];
  const float* cwv = (const float*)d_in[15];
  const float* cbv = (const float*)d_in[16];
  const float* nw  = (const float*)d_in[17];
  const float* Wg  = (const float*)d_in[18];
  const float* bg  = (const float*)d_in[19];
  const float* Wo  = (const float*)d_in[20];
  const float* bo  = (const float*)d_in[21];

  float* ws    = (float*)d_ws;
  float* lin_q = ws;               // f32; reused as gdn after conv
  float* lin_k = ws + ND_;         // f32; reused as khT/Xg/Ag/gg after conv
  float* lin_v = ws + 2 * ND_;     // f32; reused as h (bf16) after scan
  float* lin_g = ws + 3 * ND_;
  float* vb    = ws + 4 * ND_;
  u16*   qh    = (u16*)(ws + 5 * ND_);   // ND_ u16
  u16*   kh    = qh + ND_;               // ND_ u16
  float* alpha = ws + 6 * ND_;
  float* beta  = alpha + N_;
  u16*   xb    = (u16*)(beta + N_);
  u16*   wq_b  = xb + ND_;
  u16*   wk_b  = wq_b + 512 * 512;
  u16*   wv_b  = wk_b + 512 * 512;
  u16*   wg_b  = wv_b + 512 * 512;
  u16*   wo_b  = wg_b + 512 * 512;

  u16*   khT   = (u16*)lin_k;            // ND_ u16
  u16*   Xg    = khT + ND_;              // 512*1024 u16
  u16*   Ag    = Xg + (size_t)512 * 1024;
  float* gg    = (float*)(Ag + (size_t)512 * 1024);  // 512*64 f32
  float* gdn   = lin_q;
  u16*   h     = (u16*)lin_v;

  const int NW = 512 * 512;
  cvt_bf16<<<(int)(ND_ / 1024), 256, 0, stream>>>(x, xb, (int)ND_);
  cvt_bf16<<<NW / 1024, 256, 0, stream>>>(Wq, wq_b, NW);
  cvt_bf16<<<NW / 1024, 256, 0, stream>>>(Wk, wk_b, NW);
  cvt_bf16<<<NW / 1024, 256, 0, stream>>>(Wv, wv_b, NW);
  cvt_bf16<<<NW / 1024, 256, 0, stream>>>(Wg, wg_b, NW);
  cvt_bf16<<<NW / 1024, 256, 0, stream>>>(Wo, wo_b, NW);

  dim3 gg4(128, 4);
  gemm_bt<<<gg4, 256, 0, stream>>>(xb, wq_b, bq, lin_q);
  gemm_bt<<<gg4, 256, 0, stream>>>(xb, wk_b, bk, lin_k);
  gemm_bt<<<gg4, 256, 0, stream>>>(xb, wv_b, bv, lin_v);
  gemm_bt<<<gg4, 256, 0, stream>>>(xb, wg_b, bg, lin_g);
  ab_kernel<<<N_ / 4, 256, 0, stream>>>(x, Wa, ba, Wb, bb, alpha, beta);
  conv_act<<<dim3(N_, 3), 256, 0, stream>>>(lin_q, lin_k, lin_v,
                                            cwq, cbq, cwk, cbk, cwv, cbv, qh, kh, vb);
  transpose_k<<<dim3(S_ / 64, D_ / 64, B_), 256, 0, stream>>>(kh, khT);
  prepass<<<B_ * NC_, 256, 0, stream>>>(kh, qh, alpha, beta, Xg, Ag, gg);
  scan_chunk<<<dim3(D_ / SV_, B_), 512, 0, stream>>>(kh, qh, khT, vb, beta,
                                                     Xg, Ag, gg, gdn);
  norm_gate<<<N_, 256, 0, stream>>>(gdn, lin_g, nw, h);
  gemm_bt<<<gg4, 256, 0, stream>>>(h, wo_b, bo, (float*)d_out);
}

// Round 7
// 600.360 us; speedup vs baseline: 1.3548x; 1.3548x over previous
//
#include <hip/hip_runtime.h>
#include <math.h>

typedef unsigned short u16;
typedef unsigned int u32;
typedef short short8 __attribute__((ext_vector_type(8)));
typedef float f32x4 __attribute__((ext_vector_type(4)));

#define B_ 8
#define S_ 2048
#define D_ 512
#define N_ (B_ * S_)
#define ND_ ((size_t)N_ * D_)
#define CC_ 32              // chunk length
#define NC_ (S_ / CC_)      // 64 chunks
#define SV_ 16              // v-rows per scan block

__device__ __forceinline__ u16 f2bf(float f) {
  union { float f; u32 i; } v; v.f = f;
  u32 i = v.i;
  i += 0x7FFFu + ((i >> 16) & 1u);   // round-to-nearest-even
  return (u16)(i >> 16);
}
__device__ __forceinline__ float bf2f(u16 u) {
  union { u32 i; float f; } v; v.i = ((u32)u) << 16; return v.f;
}
__device__ __forceinline__ float sigm(float x) { return 1.0f / (1.0f + expf(-x)); }

// ---------------------------------------------------------------------------
// f32 -> bf16 conversion
// ---------------------------------------------------------------------------
__global__ __launch_bounds__(256) void cvt_bf16(const float* __restrict__ s,
                                                u16* __restrict__ d, int n)
{
  const int i = (blockIdx.x * 256 + threadIdx.x) * 4;
  if (i < n) {
    const float4 v = *(const float4*)(s + i);
    ushort4 o;
    o.x = f2bf(v.x); o.y = f2bf(v.y); o.z = f2bf(v.z); o.w = f2bf(v.w);
    *(ushort4*)(d + i) = o;
  }
}

// ---------------------------------------------------------------------------
// GEMM: out[m,n] = sum_k A[m,k]*W[n,k] + bias[n]; bf16 in, f32 out.
// ---------------------------------------------------------------------------
__global__ __launch_bounds__(256) void gemm_bt(
    const u16* __restrict__ A, const u16* __restrict__ W,
    const float* __restrict__ bias, float* __restrict__ out)
{
  __shared__ u16 As[128 * 40];
  __shared__ u16 Bs[128 * 40];
  const int tid = threadIdx.x;
  const int lane = tid & 63, wave = tid >> 6;
  const int wm = (wave >> 1) * 64, wn = (wave & 1) * 64;
  const int l15 = lane & 15, quad = lane >> 4;
  const int m0 = blockIdx.x * 128, n0 = blockIdx.y * 128;
  const int r0 = tid >> 2;
  const int kc0 = (tid & 3) * 8;

  f32x4 acc[4][4];
#pragma unroll
  for (int i = 0; i < 4; i++)
#pragma unroll
    for (int j = 0; j < 4; j++) acc[i][j] = (f32x4){0.f, 0.f, 0.f, 0.f};

  for (int k0 = 0; k0 < 512; k0 += 32) {
    uint4 a0 = *(const uint4*)(A + (size_t)(m0 + r0) * 512 + k0 + kc0);
    uint4 a1 = *(const uint4*)(A + (size_t)(m0 + r0 + 64) * 512 + k0 + kc0);
    uint4 b0 = *(const uint4*)(W + (size_t)(n0 + r0) * 512 + k0 + kc0);
    uint4 b1 = *(const uint4*)(W + (size_t)(n0 + r0 + 64) * 512 + k0 + kc0);
    __syncthreads();
    *(uint4*)(As + r0 * 40 + kc0) = a0;
    *(uint4*)(As + (r0 + 64) * 40 + kc0) = a1;
    *(uint4*)(Bs + r0 * 40 + kc0) = b0;
    *(uint4*)(Bs + (r0 + 64) * 40 + kc0) = b1;
    __syncthreads();
    short8 af[4], bf[4];
#pragma unroll
    for (int mt = 0; mt < 4; mt++) af[mt] = *(const short8*)(As + (wm + mt * 16 + l15) * 40 + quad * 8);
#pragma unroll
    for (int nt = 0; nt < 4; nt++) bf[nt] = *(const short8*)(Bs + (wn + nt * 16 + l15) * 40 + quad * 8);
#pragma unroll
    for (int mt = 0; mt < 4; mt++)
#pragma unroll
      for (int nt = 0; nt < 4; nt++)
        acc[mt][nt] = __builtin_amdgcn_mfma_f32_16x16x32_bf16(af[mt], bf[nt], acc[mt][nt], 0, 0, 0);
  }
#pragma unroll
  for (int mt = 0; mt < 4; mt++) {
#pragma unroll
    for (int nt = 0; nt < 4; nt++) {
      const int col = n0 + wn + nt * 16 + l15;
      const float bcol = bias[col];
#pragma unroll
      for (int r = 0; r < 4; r++) {
        const int row = m0 + wm + mt * 16 + quad * 4 + r;
        out[(size_t)row * 512 + col] = acc[mt][nt][r] + bcol;
      }
    }
  }
}

// ---------------------------------------------------------------------------
// alpha/beta
// ---------------------------------------------------------------------------
__global__ __launch_bounds__(256) void ab_kernel(
    const float* __restrict__ x, const float* __restrict__ Wa, const float* __restrict__ ba,
    const float* __restrict__ Wb, const float* __restrict__ bb,
    float* __restrict__ alpha, float* __restrict__ beta)
{
  const int lane = threadIdx.x & 63, wave = threadIdx.x >> 6;
  const int row = blockIdx.x * 4 + wave;
  const float4 x0 = *(const float4*)(x + (size_t)row * 512 + lane * 8);
  const float4 x1 = *(const float4*)(x + (size_t)row * 512 + lane * 8 + 4);
  const float4 a0 = *(const float4*)(Wa + lane * 8);
  const float4 a1 = *(const float4*)(Wa + lane * 8 + 4);
  const float4 b0 = *(const float4*)(Wb + lane * 8);
  const float4 b1 = *(const float4*)(Wb + lane * 8 + 4);
  float da = x0.x*a0.x + x0.y*a0.y + x0.z*a0.z + x0.w*a0.w
           + x1.x*a1.x + x1.y*a1.y + x1.z*a1.z + x1.w*a1.w;
  float db = x0.x*b0.x + x0.y*b0.y + x0.z*b0.z + x0.w*b0.w
           + x1.x*b1.x + x1.y*b1.y + x1.z*b1.z + x1.w*b1.w;
#pragma unroll
  for (int m = 32; m >= 1; m >>= 1) { da += __shfl_xor(da, m, 64); db += __shfl_xor(db, m, 64); }
  if (lane == 0) {
    alpha[row] = sigm(da + ba[0]);
    beta[row]  = sigm(db + bb[0]);
  }
}

// ---------------------------------------------------------------------------
// causal depthwise conv (k=4) + SiLU (+ L2 norm for q,k -> bf16; v -> f32)
// ---------------------------------------------------------------------------
__global__ __launch_bounds__(256) void conv_act(
    const float* __restrict__ lq, const float* __restrict__ lk, const float* __restrict__ lv,
    const float* __restrict__ cwq, const float* __restrict__ cbq,
    const float* __restrict__ cwk, const float* __restrict__ cbk,
    const float* __restrict__ cwv, const float* __restrict__ cbv,
    u16* __restrict__ oq, u16* __restrict__ ok, float* __restrict__ ov)
{
  __shared__ float red[4];
  const int row = blockIdx.x;
  const int z = blockIdx.y;
  const int b = row / S_, t = row - b * S_;
  const float* lin = (z == 0) ? lq : (z == 1) ? lk : lv;
  const float* cw = (z == 0) ? cwq : (z == 1) ? cwk : cwv;
  const float* cb = (z == 0) ? cbq : (z == 1) ? cbk : cbv;
  const int tid = threadIdx.x;
  float s[2]; float ssq = 0.f;
#pragma unroll
  for (int e = 0; e < 2; e++) {
    const int ch = tid + e * 256;
    float acc = cb[ch];
#pragma unroll
    for (int tau = 0; tau < 4; tau++) {
      const int tt = t - 3 + tau;
      if (tt >= 0) acc = fmaf(lin[(size_t)(b * S_ + tt) * D_ + ch], cw[ch * 4 + tau], acc);
    }
    const float sv = acc * sigm(acc);
    s[e] = sv; ssq = fmaf(sv, sv, ssq);
  }
  if (z < 2) {
    float v = ssq;
#pragma unroll
    for (int m = 32; m >= 1; m >>= 1) v += __shfl_xor(v, m, 64);
    if ((tid & 63) == 0) red[tid >> 6] = v;
    __syncthreads();
    const float tot = red[0] + red[1] + red[2] + red[3];
    const float scale = 1.0f / fmaxf(sqrtf(tot), 1e-12f);
    u16* outp = (z == 0) ? oq : ok;
    outp[(size_t)row * D_ + tid] = f2bf(s[0] * scale);
    outp[(size_t)row * D_ + tid + 256] = f2bf(s[1] * scale);
  } else {
    ov[(size_t)row * D_ + tid] = s[0];
    ov[(size_t)row * D_ + tid + 256] = s[1];
  }
}

// ---------------------------------------------------------------------------
// transpose kh [b,t,ch] -> khT [b,ch,t]  (bf16), 64x64 tiles
// ---------------------------------------------------------------------------
__global__ __launch_bounds__(256) void transpose_k(
    const u16* __restrict__ kh, u16* __restrict__ khT)
{
  __shared__ u16 T[64][68];
  const int b = blockIdx.z;
  const int t0 = blockIdx.x * 64;
  const int c0 = blockIdx.y * 64;
  const int tid = threadIdx.x;
  const int tr = tid >> 4;
  const int c4 = (tid & 15) * 4;
#pragma unroll
  for (int i = 0; i < 4; i++) {
    const int t = tr + i * 16;
    ushort4 v = *(const ushort4*)(kh + ((size_t)(b * S_ + t0 + t)) * 512 + c0 + c4);
    T[c4 + 0][t] = v.x; T[c4 + 1][t] = v.y; T[c4 + 2][t] = v.z; T[c4 + 3][t] = v.w;
  }
  __syncthreads();
#pragma unroll
  for (int i = 0; i < 4; i++) {
    const int ch = tr + i * 16;
    ushort4 v = *(const ushort4*)&T[ch][c4];
    *(ushort4*)(khT + ((size_t)(b * 512 + c0 + ch)) * S_ + t0 + c4) = v;
  }
}

// ---------------------------------------------------------------------------
// prepass: per (b,chunk):
//   X = (I+M)^-1 (32x32), A_ts = (q_t.k_s) e^{cum_t-cum_s} (s<=t) -> Ag bf16,
//   gamma tables -> gg, U = X*betaV (f32, written IN PLACE over vb),
//   Wc = X*beta*diag(gamma)*K (bf16).
// grid: 512 blocks (b*64+c), 256 threads.
// ---------------------------------------------------------------------------
__global__ __launch_bounds__(256) void prepass(
    const u16* __restrict__ kh, const u16* __restrict__ qh,
    float* __restrict__ vbU,              // in: betaless V (f32); out: U
    const float* __restrict__ alpha, const float* __restrict__ beta,
    u16* __restrict__ Ag, float* __restrict__ gg, u16* __restrict__ Wc)
{
  __shared__ float KK[32][33];
  __shared__ float QK[32][33];
  __shared__ float Ml[32][33];
  __shared__ float Xs[32][33];
  __shared__ u16 Xb[32 * 40];
  __shared__ u16 VT[512 * 40];           // transposed operand [col][s]
  __shared__ float lg[32], cum[32], bet[32], gams[32];
  const int bc = blockIdx.x;
  const int b = bc >> 6, c = bc & 63;
  const int t0 = c * CC_;
  const int tid = threadIdx.x, lane = tid & 63, w = tid >> 6;
  const int l15 = lane & 15, quad = lane >> 4;
  const size_t rb = (size_t)b * S_ + t0;

  if (tid < 32) { lg[tid] = logf(alpha[b * S_ + t0 + tid]); bet[tid] = beta[b * S_ + t0 + tid]; }
  __syncthreads();
  if (tid < 32) {
    float s = 0.f;
    for (int u = 0; u <= tid; u++) s += lg[u];
    cum[tid] = s;
    gams[tid] = expf(s);
  }
  // KK^T and QK^T quadrants
  const int mi = w >> 1, ni = w & 1;
  f32x4 ck = (f32x4){0.f,0.f,0.f,0.f}, cq = ck;
#pragma unroll
  for (int kt = 0; kt < 16; kt++) {
    const int kc = kt * 32 + quad * 8;
    short8 afk = *(const short8*)(kh + (rb + mi * 16 + l15) * 512 + kc);
    short8 afq = *(const short8*)(qh + (rb + mi * 16 + l15) * 512 + kc);
    short8 bk  = *(const short8*)(kh + (rb + ni * 16 + l15) * 512 + kc);
    ck = __builtin_amdgcn_mfma_f32_16x16x32_bf16(afk, bk, ck, 0, 0, 0);
    cq = __builtin_amdgcn_mfma_f32_16x16x32_bf16(afq, bk, cq, 0, 0, 0);
  }
#pragma unroll
  for (int r = 0; r < 4; r++) {
    KK[mi * 16 + quad * 4 + r][ni * 16 + l15] = ck[r];
    QK[mi * 16 + quad * 4 + r][ni * 16 + l15] = cq[r];
  }
  __syncthreads();
  if (tid < 32) {
    gg[(size_t)bc * 64 + tid] = gams[tid];
    gg[(size_t)bc * 64 + 32 + tid] = expf(cum[31] - cum[tid]);
  }
#pragma unroll
  for (int rep = 0; rep < 4; rep++) {
    const int e = tid + rep * 256;
    const int t = e >> 5, s = e & 31;
    const float er = expf(cum[t] - cum[s]);
    Ml[t][s] = (s < t) ? bet[t] * er * KK[t][s] : 0.f;
    Ag[(size_t)bc * 1024 + t * 32 + s] = (s <= t) ? f2bf(QK[t][s] * er) : (u16)0;
  }
  // stage V^T (beta-scaled, bf16) while the solve runs next
#pragma unroll
  for (int rep = 0; rep < 8; rep++) {
    const int e = tid + rep * 256;
    const int v = e & 511, so = e >> 9;
    short8 pk;
#pragma unroll
    for (int j = 0; j < 8; j++) {
      const int s = so * 8 + j;
      pk[j] = (short)f2bf(bet[s] * vbU[(rb + s) * 512 + v]);
    }
    *(short8*)&VT[v * 40 + so * 8] = pk;
  }
  __syncthreads();
  if (w == 0 && lane < 32) {
    const int j = lane;
    Xs[0][j] = (j == 0) ? 1.f : 0.f;
    for (int t = 1; t < 32; t++) {
      float a = (t == j) ? 1.f : 0.f;
      for (int u = 0; u < t; u++) a = fmaf(-Ml[t][u], Xs[u][j], a);
      Xs[t][j] = a;
    }
  }
  __syncthreads();
#pragma unroll
  for (int rep = 0; rep < 4; rep++) {
    const int e = tid + rep * 256;
    const int t = e >> 5, s = e & 31;
    Xb[t * 40 + s] = f2bf(Xs[t][s]);
  }
  __syncthreads();
  // U = X * betaV  (m=t 2 tiles, n = 512 v cols; wave w owns 8 n-tiles)
  short8 xa[2];
  xa[0] = *(const short8*)&Xb[l15 * 40 + quad * 8];
  xa[1] = *(const short8*)&Xb[(16 + l15) * 40 + quad * 8];
#pragma unroll
  for (int ntr = 0; ntr < 8; ntr++) {
    const int nt = w * 8 + ntr;
    short8 bv = *(const short8*)&VT[(nt * 16 + l15) * 40 + quad * 8];
#pragma unroll
    for (int mt = 0; mt < 2; mt++) {
      f32x4 g = (f32x4){0.f, 0.f, 0.f, 0.f};
      g = __builtin_amdgcn_mfma_f32_16x16x32_bf16(xa[mt], bv, g, 0, 0, 0);
#pragma unroll
      for (int r = 0; r < 4; r++)
        vbU[(rb + mt * 16 + quad * 4 + r) * 512 + nt * 16 + l15] = g[r];
    }
  }
  __syncthreads();
  // refill: K^T scaled by beta*gamma (bf16)
#pragma unroll
  for (int rep = 0; rep < 8; rep++) {
    const int e = tid + rep * 256;
    const int v = e & 511, so = e >> 9;
    short8 pk;
#pragma unroll
    for (int j = 0; j < 8; j++) {
      const int s = so * 8 + j;
      pk[j] = (short)f2bf(bet[s] * gams[s] * bf2f(kh[(rb + s) * 512 + v]));
    }
    *(short8*)&VT[v * 40 + so * 8] = pk;
  }
  __syncthreads();
  // Wc = X * beta*diag(gamma)*K  (bf16 out)
#pragma unroll
  for (int ntr = 0; ntr < 8; ntr++) {
    const int nt = w * 8 + ntr;
    short8 bv = *(const short8*)&VT[(nt * 16 + l15) * 40 + quad * 8];
#pragma unroll
    for (int mt = 0; mt < 2; mt++) {
      f32x4 g = (f32x4){0.f, 0.f, 0.f, 0.f};
      g = __builtin_amdgcn_mfma_f32_16x16x32_bf16(xa[mt], bv, g, 0, 0, 0);
#pragma unroll
      for (int r = 0; r < 4; r++)
        Wc[(size_t)bc * 16384 + (mt * 16 + quad * 4 + r) * 512 + nt * 16 + l15] = f2bf(g[r]);
    }
  }
}

// ---------------------------------------------------------------------------
// chunked gated-delta scan v3: 512 thr (8 waves), SV_=16, grid (32,8)=256 blk.
// Per iter: 3 barriers, no wave-serial phase. Wave task (phase B):
// (ttile, mat{T1=Wc*S, T2=Q*S}, khalf). Phase F: all waves state-update
// (wave w owns k-rows [w*64,w*64+64)); waves 0/1 do the O GEMM -> gdn direct.
// ---------------------------------------------------------------------------
__global__ __launch_bounds__(512) void scan_chunk(
    const u16* __restrict__ qh, const u16* __restrict__ khT,
    const u16* __restrict__ Wc, const float* __restrict__ U,
    const u16* __restrict__ Ag, const float* __restrict__ gg,
    float* __restrict__ gdn)
{
  __shared__ u16 S_A[16 * 520];       // S[v][k] bf16
  __shared__ float P[2][2][32][16];   // [mat][khalf][t][v]
  __shared__ u16 Ct_T[16 * 40];       // C~^T [v][s]
  __shared__ u16 Cr_T[16 * 40];       // C~^T * (gC/gs)
  __shared__ float OB[32][17];        // gamma_t * T2 [t][v]
  __shared__ float gam[32], grc[32];
  const int b = blockIdx.y;
  const int iv0 = blockIdx.x * SV_;
  const int tid = threadIdx.x, lane = tid & 63, w = tid >> 6;
  const int l15 = lane & 15, quad = lane >> 4;
  const int ttile = w & 1, mat = (w >> 1) & 1, khalf = w >> 2;
  const size_t bS = (size_t)b * S_;
  const int ct = tid >> 4, cv = tid & 15;     // phase-C coords (32x16)

  f32x4 acc[4];
#pragma unroll
  for (int mt = 0; mt < 4; mt++) acc[mt] = (f32x4){0.f, 0.f, 0.f, 0.f};

#pragma unroll 1
  for (int c = 0; c < NC_; c++) {
    const int t0 = c * CC_;
    const int bc = b * 64 + c;
    // ---- phase A: prefetch ALL globals; dump S to LDS ----
    short8 bfrag[8];
    const u16* bsrc = mat ? (qh + (bS + t0 + ttile * 16 + l15) * 512 + khalf * 256)
                          : (Wc + ((size_t)bc * 32 + ttile * 16 + l15) * 512 + khalf * 256);
#pragma unroll
    for (int kt = 0; kt < 8; kt++)
      bfrag[kt] = *(const short8*)(bsrc + kt * 32 + quad * 8);
    short8 tk[4];
#pragma unroll
    for (int mt = 0; mt < 4; mt++)
      tk[mt] = *(const short8*)(khT + ((size_t)(b * 512 + w * 64 + mt * 16 + l15)) * S_ + t0 + quad * 8);
    const float Uv = U[(bS + t0 + ct) * 512 + iv0 + cv];
    short8 agf;
    if (w < 2) agf = *(const short8*)(Ag + (size_t)bc * 1024 + (w * 16 + l15) * 32 + quad * 8);
    if (tid < 32) { gam[tid] = gg[(size_t)bc * 64 + tid]; grc[tid] = gg[(size_t)bc * 64 + 32 + tid]; }
#pragma unroll
    for (int mt = 0; mt < 4; mt++) {
      ushort4 p;
      p.x = f2bf(acc[mt][0]); p.y = f2bf(acc[mt][1]);
      p.z = f2bf(acc[mt][2]); p.w = f2bf(acc[mt][3]);
      *(ushort4*)&S_A[l15 * 520 + w * 64 + mt * 16 + quad * 4] = p;
    }
    __syncthreads();
    // ---- phase B: one MFMA task per wave (8 MFMAs over its k-half) ----
    f32x4 g = (f32x4){0.f, 0.f, 0.f, 0.f};
#pragma unroll
    for (int kt = 0; kt < 8; kt++) {
      short8 af = *(const short8*)&S_A[l15 * 520 + khalf * 256 + kt * 32 + quad * 8];
      g = __builtin_amdgcn_mfma_f32_16x16x32_bf16(af, bfrag[kt], g, 0, 0, 0);
    }
    *(f32x4*)&P[mat][khalf][ttile * 16 + l15][quad * 4] = g;
    __syncthreads();
    // ---- phase C: 2-way reduce, C~ = U - T1, OB = gam*T2 ----
    const float gCs = gam[31];
    {
      const float T1 = P[0][0][ct][cv] + P[0][1][ct][cv];
      const float T2 = P[1][0][ct][cv] + P[1][1][ct][cv];
      const float ctv = Uv - T1;
      Ct_T[cv * 40 + ct] = f2bf(ctv);
      Cr_T[cv * 40 + ct] = f2bf(ctv * grc[ct]);
      OB[ct][cv] = gam[ct] * T2;
    }
    __syncthreads();
    // ---- phase F: state update (all waves); O GEMM (waves 0,1) -> gdn ----
    short8 bcf = *(const short8*)&Cr_T[l15 * 40 + quad * 8];
#pragma unroll
    for (int mt = 0; mt < 4; mt++) {
      acc[mt] = acc[mt] * gCs;
      acc[mt] = __builtin_amdgcn_mfma_f32_16x16x32_bf16(tk[mt], bcf, acc[mt], 0, 0, 0);
    }
    if (w < 2) {
      short8 ctf = *(const short8*)&Ct_T[l15 * 40 + quad * 8];
      f32x4 oo;
#pragma unroll
      for (int r = 0; r < 4; r++) oo[r] = OB[w * 16 + quad * 4 + r][l15];
      oo = __builtin_amdgcn_mfma_f32_16x16x32_bf16(agf, ctf, oo, 0, 0, 0);
#pragma unroll
      for (int r = 0; r < 4; r++)
        gdn[(bS + t0 + w * 16 + quad * 4 + r) * 512 + iv0 + l15] = oo[r];
    }
  }
}

// ---------------------------------------------------------------------------
// zero-centered rmsnorm * norm_w * silu(gate) -> bf16 h
// ---------------------------------------------------------------------------
__global__ __launch_bounds__(256) void norm_gate(
    const float* __restrict__ gdn, const float* __restrict__ lg,
    const float* __restrict__ nw, u16* __restrict__ h)
{
  __shared__ float red[8];
  const int row = blockIdx.x, tid = threadIdx.x;
  const size_t base = (size_t)row * D_;
  const float g0 = gdn[base + tid], g1 = gdn[base + tid + 256];
  float sm = g0 + g1;
#pragma unroll
  for (int m = 32; m >= 1; m >>= 1) sm += __shfl_xor(sm, m, 64);
  if ((tid & 63) == 0) red[tid >> 6] = sm;
  __syncthreads();
  const float mean = (red[0] + red[1] + red[2] + red[3]) * (1.0f / 512.0f);
  const float x0 = g0 - mean, x1 = g1 - mean;
  float sq = x0 * x0 + x1 * x1;
#pragma unroll
  for (int m = 32; m >= 1; m >>= 1) sq += __shfl_xor(sq, m, 64);
  if ((tid & 63) == 0) red[4 + (tid >> 6)] = sq;
  __syncthreads();
  const float var = (red[4] + red[5] + red[6] + red[7]) * (1.0f / 512.0f);
  const float rst = rsqrtf(var + 1e-5f);
  const float gl0 = lg[base + tid];
  h[base + tid] = f2bf(x0 * rst * nw[tid] * (gl0 * sigm(gl0)));
  const float gl1 = lg[base + tid + 256];
  h[base + tid + 256] = f2bf(x1 * rst * nw[tid + 256] * (gl1 * sigm(gl1)));
}

// ---------------------------------------------------------------------------
extern "C" void kernel_launch(void* const* d_in, const int* in_sizes, int n_in,
                              void* d_out, int out_size, void* d_ws, size_t ws_size,
                              hipStream_t stream)
{
  const float* x   = (const float*)d_in[0];
  const float* Wq  = (const float*)d_in[1];
  const float* bq  = (const float*)d_in[2];
  const float* Wk  = (const float*)d_in[3];
  const float* bk  = (const float*)d_in[4];
  const float* Wv  = (const float*)d_in[5];
  const float* bv  = (const float*)d_in[6];
  const float* Wa  = (const float*)d_in[7];
  const float* ba  = (const float*)d_in[8];
  const float* Wb  = (const float*)d_in[9];
  const float* bb  = (const float*)d_in[10];
  const float* cwq = (const float*)d_in[11];
  const float* cbq = (const float*)d_in[12];
  const float* cwk = (const float*)d_in[13];
  const float* cbk = (const float*)d_in[14];
  const float* cwv = (const float*)d_in[15];
  const float* cbv = (const float*)d_in[16];
  const float* nw  = (const float*)d_in[17];
  const float* Wg  = (const float*)d_in[18];
  const float* bg  = (const float*)d_in[19];
  const float* Wo  = (const float*)d_in[20];
  const float* bo  = (const float*)d_in[21];

  float* ws    = (float*)d_ws;
  float* lin_q = ws;               // f32; reused as gdn after conv
  float* lin_k = ws + ND_;         // f32; reused as khT/Ag/gg after conv
  float* lin_v = ws + 2 * ND_;     // f32; reused as Wc (prepass), then h
  float* lin_g = ws + 3 * ND_;
  float* vb    = ws + 4 * ND_;     // f32 v; overwritten IN PLACE by U in prepass
  u16*   qh    = (u16*)(ws + 5 * ND_);   // ND_ u16
  u16*   kh    = qh + ND_;               // ND_ u16
  float* alpha = ws + 6 * ND_;
  float* beta  = alpha + N_;
  u16*   xb    = (u16*)(beta + N_);
  u16*   wq_b  = xb + ND_;
  u16*   wk_b  = wq_b + 512 * 512;
  u16*   wv_b  = wk_b + 512 * 512;
  u16*   wg_b  = wv_b + 512 * 512;
  u16*   wo_b  = wg_b + 512 * 512;

  u16*   khT   = (u16*)lin_k;            // ND_ u16 (16MB)
  u16*   Agb   = khT + ND_;              // 512*1024 u16 (1MB)
  float* ggb   = (float*)(Agb + (size_t)512 * 1024);  // 512*64 f32
  u16*   Wcb   = (u16*)lin_v;            // 512*32*512 u16 (16MB)
  float* gdn   = lin_q;
  u16*   h     = (u16*)lin_v;            // written after Wc consumed

  const int NW = 512 * 512;
  cvt_bf16<<<(int)(ND_ / 1024), 256, 0, stream>>>(x, xb, (int)ND_);
  cvt_bf16<<<NW / 1024, 256, 0, stream>>>(Wq, wq_b, NW);
  cvt_bf16<<<NW / 1024, 256, 0, stream>>>(Wk, wk_b, NW);
  cvt_bf16<<<NW / 1024, 256, 0, stream>>>(Wv, wv_b, NW);
  cvt_bf16<<<NW / 1024, 256, 0, stream>>>(Wg, wg_b, NW);
  cvt_bf16<<<NW / 1024, 256, 0, stream>>>(Wo, wo_b, NW);

  dim3 gg4(128, 4);
  gemm_bt<<<gg4, 256, 0, stream>>>(xb, wq_b, bq, lin_q);
  gemm_bt<<<gg4, 256, 0, stream>>>(xb, wk_b, bk, lin_k);
  gemm_bt<<<gg4, 256, 0, stream>>>(xb, wv_b, bv, lin_v);
  gemm_bt<<<gg4, 256, 0, stream>>>(xb, wg_b, bg, lin_g);
  ab_kernel<<<N_ / 4, 256, 0, stream>>>(x, Wa, ba, Wb, bb, alpha, beta);
  conv_act<<<dim3(N_, 3), 256, 0, stream>>>(lin_q, lin_k, lin_v,
                                            cwq, cbq, cwk, cbk, cwv, cbv, qh, kh, vb);
  transpose_k<<<dim3(S_ / 64, D_ / 64, B_), 256, 0, stream>>>(kh, khT);
  prepass<<<B_ * NC_, 256, 0, stream>>>(kh, qh, vb, alpha, beta, Agb, ggb, Wcb);
  scan_chunk<<<dim3(D_ / SV_, B_), 512, 0, stream>>>(qh, khT, Wcb, vb, Agb, ggb, gdn);
  norm_gate<<<N_, 256, 0, stream>>>(gdn, lin_g, nw, h);
  gemm_bt<<<gg4, 256, 0, stream>>>(h, wo_b, bo, (float*)d_out);
}